// Round 8
// baseline (281.412 us; speedup 1.0000x reference)
//
#include <hip/hip_runtime.h>
#include <hip/hip_bf16.h>

typedef __bf16 bf16x8 __attribute__((ext_vector_type(8)));
typedef float f32x4 __attribute__((ext_vector_type(4)));
typedef float f32x16 __attribute__((ext_vector_type(16)));
typedef int int32x8 __attribute__((ext_vector_type(8)));

#define N 8192
#define D 512
#define NS 64

// workspace layout (bytes) — ~21 MB
#define XS_OFF 0                            // fp8 X [N][512 B] plain K-major : 4 MB
#define WT_OFF (4 * 1024 * 1024)            // bf16 WT chunked [256][64s][32i] : 1 MB
#define SQ_OFF (WT_OFF + 1024 * 1024)       // f32 sq [N] : 32 KB
#define EP_OFF (SQ_OFF + 32 * 1024)         // f32 Ep [8 chunk][64 s][8192 n] : 16 MB
#define SC_OFF (EP_OFF + 8 * 64 * 8192 * 4) // f32 S1,S2 + int cnt

#define SCALE1 0x7F7F7F7F   // E8M0 = 127 -> 2^0 in every byte (unit scale)

// ---------------------------------------------------------------------------
// fused prep (blocks [0,2048): X -> fp8 plain K-major + sq;
//             [2048,2176): W -> chunked bf16 W^T)
__global__ __launch_bounds__(256) void prep(const float* __restrict__ X,
                                            const float* __restrict__ W,
                                            unsigned char* __restrict__ Xs,
                                            float* __restrict__ sq,
                                            __bf16* __restrict__ WTs,
                                            float* __restrict__ Sacc) {
    __shared__ float T[64][65];
    int t = threadIdx.x;
    if (blockIdx.x == 0 && t == 0) {        // zero loss accumulators + counter
        Sacc[0] = 0.f; Sacc[1] = 0.f; ((int*)Sacc)[2] = 0;
    }
    if (blockIdx.x < 2048) {
        int row = blockIdx.x * 4 + (t >> 6);
        int l = t & 63;
        const float* src = X + (size_t)row * D + l * 8;
        float4 v0 = *(const float4*)src;
        float4 v1 = *(const float4*)(src + 4);
        int w0 = __builtin_amdgcn_cvt_pk_fp8_f32(v0.x, v0.y, 0, false);
        w0     = __builtin_amdgcn_cvt_pk_fp8_f32(v0.z, v0.w, w0, true);
        int w1 = __builtin_amdgcn_cvt_pk_fp8_f32(v1.x, v1.y, 0, false);
        w1     = __builtin_amdgcn_cvt_pk_fp8_f32(v1.z, v1.w, w1, true);
        uint2 pk = make_uint2((unsigned)w0, (unsigned)w1);
        *(uint2*)(Xs + (size_t)row * 512 + l * 8) = pk;     // plain K-major
        float acc = v0.x*v0.x + v0.y*v0.y + v0.z*v0.z + v0.w*v0.w
                  + v1.x*v1.x + v1.y*v1.y + v1.z*v1.z + v1.w*v1.w;
        for (int off = 32; off > 0; off >>= 1) acc += __shfl_down(acc, off);
        if (l == 0) sq[row] = acc;
    } else {
        int i0 = (blockIdx.x - 2048) * 64;
        for (int j = 0; j < 16; ++j) {
            int idx = t + 256 * j;
            T[idx & 63][idx >> 6] = W[(size_t)(i0 + (idx >> 6)) * NS + (idx & 63)];
        }
        __syncthreads();
        for (int h = 0; h < 2; ++h)
            for (int j = 0; j < 8; ++j) {
                int idx = t + 256 * j;                  // 0..2047
                int s = idx >> 5, il = idx & 31;
                WTs[(size_t)((i0 >> 5) + h) * 2048 + idx] = (__bf16)T[s][h * 32 + il];
            }
    }
}

// ---------------------------------------------------------------------------
// main: grid (64 n-blocks, 8 i-chunks). Per block, 8 its of 128 i:
//  n-STRIP decomposition: wave w owns n in [n0+w*32, n0+w*32+32) for BOTH
//  Gram and E phases. Gram 128x128 via MX fp8 mfma_scale_32x32x64 (unit
//  scales, verified r6): per kc, 4 MFMAs (mt=i-tile 0..3) x 1 B-frag.
//  B-frag regs: bc[4] (32 VGPR, kc 0..3) + persistent XnHi LDS panel (kc 4..7).
//  Xi double-buffered 80-B-padded LDS, coalesced staging, 1 barrier/kc,
//  1-step prefetch (round-5 proven). exp epilogue -> KT halves [128][72];
//  E-phase 16x16x32 bf16 (round-5 verbatim). E partials: plain stores.
__global__ __launch_bounds__(256, 2) void kpca_main(
        const unsigned char* __restrict__ Xs, const __bf16* __restrict__ WTs,
        const float* __restrict__ sq, float* __restrict__ Ep) {
    __shared__ __align__(16) unsigned char Xi[2][128 * 80];   // [128][64+16 pad]
    __shared__ __align__(16) unsigned char XnHi[128 * 272];   // rows: 256 B data +16 pad
    __shared__ __align__(16) __bf16 KT[128 * 72];             // [n][72] (64 i + 8 pad)

    const int t = threadIdx.x;
    const int w = t >> 6, l = t & 63;
    const int quad = l >> 4, l15 = l & 15;
    const int l31 = l & 31, lh = l >> 5;        // 32x32 frag coords
    const int n0 = blockIdx.x * 128;
    const int ic0 = blockIdx.y * 1024;

    // ---- prologue: B-frag VGPR cache (kc 0..3) for this wave's n-strip
    int32x8 bc[4];
    {
        const unsigned char* Bb = Xs + (size_t)(n0 + w * 32 + l31) * 512 + lh * 32;
        #pragma unroll
        for (int k8 = 0; k8 < 4; ++k8)
            bc[k8] = *(const int32x8*)(Bb + k8 * 64);
    }
    // persistent XnHi (kc 4..7): bytes 256..511 of all 128 n-rows
    {
        int r = t >> 1, h = t & 1;
        const unsigned char* g = Xs + (size_t)(n0 + r) * 512 + 256 + h * 128;
        unsigned char* d = XnHi + r * 272 + h * 128;
        #pragma unroll
        for (int j = 0; j < 8; ++j)
            *(uint4*)(d + j * 16) = *(const uint4*)(g + j * 16);
    }
    const float sqn = sq[n0 + w * 32 + l31];

    f32x4 accE[4][2];
    for (int st = 0; st < 4; ++st)
        for (int n2 = 0; n2 < 2; ++n2)
            accE[st][n2] = (f32x4){0.f, 0.f, 0.f, 0.f};

    // staging geometry: thread stages 2 x 16 B (rows 0..63 and 64..127)
    const int ra = t >> 2, blk = (t & 3) * 16;
    const int lo = ra * 80 + blk;               // padded LDS offset (row stride 80)

    // preload tile (it=0, kc=0) into buf0
    {
        const unsigned char* g = Xs + (size_t)(ic0 + ra) * 512 + blk;
        *(uint4*)(Xi[0] + lo)           = *(const uint4*)g;
        *(uint4*)(Xi[0] + lo + 64 * 80) = *(const uint4*)(g + 64 * 512);
    }

    for (int it = 0; it < 8; ++it) {
        const int i0 = ic0 + it * 128;

        f32x16 accG[4];                 // mt = 0..3 (i-tiles); n = this strip
        for (int mt = 0; mt < 4; ++mt)
            for (int r = 0; r < 16; ++r) accG[mt][r] = 0.f;

        #pragma unroll
        for (int kc = 0; kc < 8; ++kc) {
            // prefetch next tile (full kc-step of latency hiding)
            uint4 qA, qB;
            const bool stage = (kc < 7) || (it < 7);
            if (stage) {
                const int kn = (kc + 1) & 7;
                const int i0n = i0 + ((kc == 7) ? 128 : 0);
                const unsigned char* g = Xs + (size_t)(i0n + ra) * 512 + kn * 64 + blk;
                qA = *(const uint4*)g;
                qB = *(const uint4*)(g + 64 * 512);
            }
            __syncthreads();   // buf[kc&1] stores visible; prior reads of other buf done
            const unsigned char* xb = Xi[kc & 1];
            int32x8 b;
            if (kc < 4) b = bc[kc];
            else        b = *(const int32x8*)(XnHi + (w * 32 + l31) * 272 +
                                              (kc - 4) * 64 + lh * 32);
            #pragma unroll
            for (int mt = 0; mt < 4; ++mt) {
                int32x8 a = *(const int32x8*)(xb + (mt * 32 + l31) * 80 + lh * 32);
                accG[mt] = __builtin_amdgcn_mfma_scale_f32_32x32x64_f8f6f4(
                    a, b, accG[mt],
                    0, 0,                    // cbsz=fp8(e4m3), blgp=fp8
                    0, SCALE1, 0, SCALE1);   // unit scales
            }
            if (stage) {
                unsigned char* xd = Xi[(kc + 1) & 1];
                *(uint4*)(xd + lo)           = qA;
                *(uint4*)(xd + lo + 64 * 80) = qB;
            }
        }

        // ---- epilogue: d2 -> exp -> packed bf16 (accG dies here)
        // 32x32 C layout (verified r6): col = l31 (n), row = (reg&3)+8*(reg>>2)+4*lh
        uint2 pk[4][4];
        #pragma unroll
        for (int mt = 0; mt < 4; ++mt)
            #pragma unroll
            for (int rq = 0; rq < 4; ++rq) {
                const int ib = mt * 32 + 8 * rq + 4 * lh;     // i-local
                f32x4 si = *(const f32x4*)(sq + i0 + ib);
                union { __bf16 h[4]; uint2 u; } u;
                #pragma unroll
                for (int rr = 0; rr < 4; ++rr) {
                    float d2 = si[rr] + sqn - 2.0f * accG[mt][rq * 4 + rr];
                    u.h[rr] = (__bf16)__expf(d2 * -9.765625e-4f);  // exp(-d2/1024)
                }
                pk[mt][rq] = u.u;
            }

        // W^T frags for E-phase, first half (i-chunks 0,1) — global, L2-hot
        const __bf16* wslab = WTs + (size_t)(i0 >> 5) * 2048;
        bf16x8 aw[2][4];
        #pragma unroll
        for (int kc2 = 0; kc2 < 2; ++kc2)
            for (int st = 0; st < 4; ++st)
                aw[kc2][st] = *(const bf16x8*)(wslab + kc2 * 2048 +
                                               (st * 16 + l15) * 32 + quad * 8);

        __syncthreads();   // A: prev it's E-phase KT reads done
        // half 0: i-local 0..63 (mt 0,1); every wave writes its own n-rows
        #pragma unroll
        for (int mt = 0; mt < 2; ++mt)
            for (int rq = 0; rq < 4; ++rq)
                *(uint2*)(KT + (w * 32 + l31) * 72 + mt * 32 + 8 * rq + 4 * lh)
                    = pk[mt][rq];
        __syncthreads();   // B: KT half-0 visible
        #pragma unroll
        for (int kc2 = 0; kc2 < 2; ++kc2) {
            bf16x8 bk[2];
            for (int n2 = 0; n2 < 2; ++n2)
                bk[n2] = *(const bf16x8*)(KT + (w * 32 + n2 * 16 + l15) * 72 +
                                          kc2 * 32 + quad * 8);
            #pragma unroll
            for (int st = 0; st < 4; ++st)
                for (int n2 = 0; n2 < 2; ++n2)
                    accE[st][n2] = __builtin_amdgcn_mfma_f32_16x16x32_bf16(
                        aw[kc2][st], bk[n2], accE[st][n2], 0, 0, 0);
        }
        #pragma unroll
        for (int kc2 = 0; kc2 < 2; ++kc2)      // second half (i-chunks 2,3)
            for (int st = 0; st < 4; ++st)
                aw[kc2][st] = *(const bf16x8*)(wslab + (kc2 + 2) * 2048 +
                                               (st * 16 + l15) * 32 + quad * 8);
        __syncthreads();   // C: half-0 E reads done
        // half 1: i-local 64..127 (mt 2,3)
        #pragma unroll
        for (int mt = 0; mt < 2; ++mt)
            for (int rq = 0; rq < 4; ++rq)
                *(uint2*)(KT + (w * 32 + l31) * 72 + mt * 32 + 8 * rq + 4 * lh)
                    = pk[mt + 2][rq];
        __syncthreads();   // D: KT half-1 visible
        #pragma unroll
        for (int kc2 = 0; kc2 < 2; ++kc2) {
            bf16x8 bk[2];
            for (int n2 = 0; n2 < 2; ++n2)
                bk[n2] = *(const bf16x8*)(KT + (w * 32 + n2 * 16 + l15) * 72 +
                                          kc2 * 32 + quad * 8);
            #pragma unroll
            for (int st = 0; st < 4; ++st)
                for (int n2 = 0; n2 < 2; ++n2)
                    accE[st][n2] = __builtin_amdgcn_mfma_f32_16x16x32_bf16(
                        aw[kc2][st], bk[n2], accE[st][n2], 0, 0, 0);
        }
    }

    // ---- per-chunk E partial: plain stores
    float* ep = Ep + (size_t)blockIdx.y * (NS * N);
    #pragma unroll
    for (int st = 0; st < 4; ++st)
        for (int n2 = 0; n2 < 2; ++n2)
            for (int r = 0; r < 4; ++r) {
                int s = st * 16 + quad * 4 + r;
                int n = n0 + w * 32 + n2 * 16 + l15;
                ep[(size_t)s * N + n] = accE[st][n2][r];
            }
}

// ---------------------------------------------------------------------------
// loss: 256 blocks = 64 s x 4 n-chunks; sums the 8 E partials, reduces;
// last block finalizes the scalar.
__global__ __launch_bounds__(256) void loss_kernel(const float* __restrict__ Ep,
                                                   const __bf16* __restrict__ WTs,
                                                   const float* __restrict__ lam,
                                                   float* __restrict__ Sacc,
                                                   float* __restrict__ out) {
    int s = blockIdx.x >> 2;
    int nb = (blockIdx.x & 3) * 2048;
    int t = threadIdx.x;
    float a1 = 0.f, a2 = 0.f;
    for (int j = 0; j < 8; ++j) {
        int n = nb + t + j * 256;
        float e = 0.f;
        #pragma unroll
        for (int c = 0; c < 8; ++c)
            e += Ep[(size_t)c * (NS * N) + (size_t)s * N + n];
        a1 += e * e;
        a2 += e * (float)WTs[(size_t)(n >> 5) * 2048 + s * 32 + (n & 31)];
    }
    for (int off = 32; off > 0; off >>= 1) {
        a1 += __shfl_down(a1, off);
        a2 += __shfl_down(a2, off);
    }
    __shared__ float r1[4], r2[4];
    int wv = t >> 6, ln = t & 63;
    if (ln == 0) { r1[wv] = a1; r2[wv] = a2; }
    __syncthreads();
    if (t == 0) {
        atomicAdd(Sacc + 0, lam[s] * (r1[0] + r1[1] + r1[2] + r1[3]));
        atomicAdd(Sacc + 1, r2[0] + r2[1] + r2[2] + r2[3]);
        __threadfence();
        int prev = atomicAdd((int*)Sacc + 2, 1);
        if (prev == 255) {                       // last block finalizes
            __threadfence();
            volatile float* vs = (volatile float*)Sacc;
            float L = 0.5f * (vs[1] - vs[0]);    // loss1=-S1/2, loss2=S2/2
            out[0] = L + 0.05f * L * L;          // C_STAB/2 = 0.05
        }
    }
}

// ---------------------------------------------------------------------------
extern "C" void kernel_launch(void* const* d_in, const int* in_sizes, int n_in,
                              void* d_out, int out_size, void* d_ws, size_t ws_size,
                              hipStream_t stream) {
    const float* X   = (const float*)d_in[0];   // [8192][512]
    const float* W   = (const float*)d_in[1];   // [8192][64]
    const float* lam = (const float*)d_in[2];   // [64]
    float* out = (float*)d_out;
    char* ws = (char*)d_ws;
    unsigned char* Xs = (unsigned char*)(ws + XS_OFF);
    __bf16* WTs = (__bf16*)(ws + WT_OFF);
    float* sq   = (float*)(ws + SQ_OFF);
    float* Ep   = (float*)(ws + EP_OFF);
    float* Sacc = (float*)(ws + SC_OFF);

    prep<<<2048 + 128, 256, 0, stream>>>(X, W, Xs, sq, WTs, Sacc);
    kpca_main<<<dim3(64, 8), 256, 0, stream>>>(Xs, WTs, sq, Ep);
    loss_kernel<<<256, 256, 0, stream>>>(Ep, WTs, lam, Sacc, out);
}

// Round 10
// 146.391 us; speedup vs baseline: 1.9223x; 1.9223x over previous
//
#include <hip/hip_runtime.h>
#include <hip/hip_bf16.h>

typedef __bf16 bf16x8 __attribute__((ext_vector_type(8)));
typedef float f32x4 __attribute__((ext_vector_type(4)));
typedef long longx2 __attribute__((ext_vector_type(2)));

#define N 8192
#define D 512
#define NS 64

// workspace layout (bytes) — ~21 MB
#define XS_OFF 0                            // fp8 X [N][512 B] k-permuted : 4 MB
#define WT_OFF (4 * 1024 * 1024)            // bf16 WT chunked [256][64s][32i] : 1 MB
#define SQ_OFF (WT_OFF + 1024 * 1024)       // f32 sq [N] : 32 KB
#define EP_OFF (SQ_OFF + 32 * 1024)         // f32 Ep [8 chunk][64 s][8192 n] : 16 MB
#define SC_OFF (EP_OFF + 8 * 64 * 8192 * 4) // f32 S1,S2 + int cnt

// ---------------------------------------------------------------------------
// fused prep (blocks [0,2048): X -> fp8 k-permuted + sq; [2048,2176): W -> WT)
// Per 64-B k-group of X, 16-B block q holds [k=q*8..+8 | k=32+q*8..+8] so one
// 16-B read = both K32-half fragments for MFMA lane quad=q.
__global__ __launch_bounds__(256) void prep(const float* __restrict__ X,
                                            const float* __restrict__ W,
                                            unsigned char* __restrict__ Xs,
                                            float* __restrict__ sq,
                                            __bf16* __restrict__ WTs,
                                            float* __restrict__ Sacc) {
    __shared__ float T[64][65];
    int t = threadIdx.x;
    if (blockIdx.x == 0 && t == 0) {        // zero loss accumulators + counter
        Sacc[0] = 0.f; Sacc[1] = 0.f; ((int*)Sacc)[2] = 0;
    }
    if (blockIdx.x < 2048) {
        int row = blockIdx.x * 4 + (t >> 6);
        int l = t & 63;
        const float* src = X + (size_t)row * D + l * 8;
        float4 v0 = *(const float4*)src;
        float4 v1 = *(const float4*)(src + 4);
        int w0 = __builtin_amdgcn_cvt_pk_fp8_f32(v0.x, v0.y, 0, false);
        w0     = __builtin_amdgcn_cvt_pk_fp8_f32(v0.z, v0.w, w0, true);
        int w1 = __builtin_amdgcn_cvt_pk_fp8_f32(v1.x, v1.y, 0, false);
        w1     = __builtin_amdgcn_cvt_pk_fp8_f32(v1.z, v1.w, w1, true);
        int g = l >> 3, kh = (l >> 2) & 1, q = l & 3;
        int pos = g * 64 + q * 16 + kh * 8;
        uint2 pk = make_uint2((unsigned)w0, (unsigned)w1);
        *(uint2*)(Xs + (size_t)row * 512 + pos) = pk;
        float acc = v0.x*v0.x + v0.y*v0.y + v0.z*v0.z + v0.w*v0.w
                  + v1.x*v1.x + v1.y*v1.y + v1.z*v1.z + v1.w*v1.w;
        for (int off = 32; off > 0; off >>= 1) acc += __shfl_down(acc, off);
        if (l == 0) sq[row] = acc;
    } else {
        int i0 = (blockIdx.x - 2048) * 64;
        for (int j = 0; j < 16; ++j) {
            int idx = t + 256 * j;
            T[idx & 63][idx >> 6] = W[(size_t)(i0 + (idx >> 6)) * NS + (idx & 63)];
        }
        __syncthreads();
        for (int h = 0; h < 2; ++h)
            for (int j = 0; j < 8; ++j) {
                int idx = t + 256 * j;                  // 0..2047
                int s = idx >> 5, il = idx & 31;
                WTs[(size_t)((i0 >> 5) + h) * 2048 + idx] = (__bf16)T[s][h * 32 + il];
            }
    }
}

// ---------------------------------------------------------------------------
// main (round-5 measured optimum): grid (64 n-blocks, 8 i-chunks).
// Per block, 8 its of 128 i:
//  - Gram 128x128 fp8 16x16x32, Xi double-buffered (1 barrier/kc8, loads
//    issued a full kc8 ahead); B-frags kc8 0..3 from VGPR cache bc (64 regs),
//    kc8 4..7 from persistent padded LDS panel XnHi.
//  - exp epilogue -> KT bf16 halves [128][72]; E-phase 16x16x32 bf16 with
//    WT frags direct from global in two 32-reg halves (no spill).
//  - E partials per i-chunk, plain stores (no memset, no atomics).
// Walls (measured r4-r9): arch-VGPR cap 128 (MX/bigger caches spill);
// frag-direct global loads uncoalesced; LDS <= 80K for 2 blocks/CU;
// E-phase must be bf16 (fp8 KT fails absmax).
__global__ __launch_bounds__(256, 2) void kpca_main(
        const unsigned char* __restrict__ Xs, const __bf16* __restrict__ WTs,
        const float* __restrict__ sq, float* __restrict__ Ep) {
    __shared__ __align__(16) unsigned char Xi[2][8192];       // [128][64] dbuf
    __shared__ __align__(16) unsigned char XnHi[128 * 272];   // 256 B data + 16 pad
    __shared__ __align__(16) __bf16 KT[128 * 72];             // [n][72] (64 i + 8 pad)

    const int t = threadIdx.x;
    const int w = t >> 6, l = t & 63;
    const int quad = l >> 4, l15 = l & 15;
    const int wm = w >> 1, wn = w & 1;
    const int n0 = blockIdx.x * 128;
    const int ic0 = blockIdx.y * 1024;

    // ---- prologue: B-frag VGPR cache (kc8 0..3) + persistent XnHi (kc8 4..7)
    longx2 bc[4][4];
    {
        const unsigned char* Bb = Xs + (size_t)(n0 + wn * 64 + l15) * 512 + quad * 16;
        #pragma unroll
        for (int k8 = 0; k8 < 4; ++k8)
            #pragma unroll
            for (int nt = 0; nt < 4; ++nt)
                bc[k8][nt] = *(const longx2*)(Bb + nt * (16 * 512) + k8 * 64);
    }
    {
        int r = t >> 1, h = t & 1;
        const unsigned char* g = Xs + (size_t)(n0 + r) * 512 + 256 + h * 128;
        unsigned char* d = XnHi + r * 272 + h * 128;
        #pragma unroll
        for (int j = 0; j < 8; ++j)
            *(uint4*)(d + j * 16) = *(const uint4*)(g + j * 16);
    }
    float sqn_v[4];
    for (int nt = 0; nt < 4; ++nt)
        sqn_v[nt] = sq[n0 + wn * 64 + nt * 16 + l15];

    f32x4 accE[4][2];
    for (int st = 0; st < 4; ++st)
        for (int n2 = 0; n2 < 2; ++n2)
            accE[st][n2] = (f32x4){0.f, 0.f, 0.f, 0.f};

    // staging geometry: thread stages 2 x 16 B (rows 0..63 and 64..127)
    const int ra = t >> 2, blk = (t & 3) * 16;

    // preload tile (it=0, kc8=0) into buf0
    {
        const unsigned char* g = Xs + (size_t)(ic0 + ra) * 512 + blk;
        *(uint4*)(Xi[0] + t * 16)        = *(const uint4*)g;
        *(uint4*)(Xi[0] + t * 16 + 4096) = *(const uint4*)(g + 64 * 512);
    }

    for (int it = 0; it < 8; ++it) {
        const int i0 = ic0 + it * 128;
        f32x4 accG[4][4];
        for (int mt = 0; mt < 4; ++mt)
            for (int nt = 0; nt < 4; ++nt)
                accG[mt][nt] = (f32x4){0.f, 0.f, 0.f, 0.f};

        #pragma unroll
        for (int kc8 = 0; kc8 < 8; ++kc8) {
            // prefetch next tile (full kc8-step of latency hiding)
            uint4 qA, qB;
            const bool stage = (kc8 < 7) || (it < 7);
            if (stage) {
                const int kn = (kc8 + 1) & 7;
                const int i0n = i0 + ((kc8 == 7) ? 128 : 0);
                const unsigned char* g = Xs + (size_t)(i0n + ra) * 512 + kn * 64 + blk;
                qA = *(const uint4*)g;
                qB = *(const uint4*)(g + 64 * 512);
            }
            __syncthreads();   // buf[kc8&1] stores visible; prior reads of other buf done
            const unsigned char* xb = Xi[kc8 & 1];
            longx2 a[4], b[4];
            #pragma unroll
            for (int mt = 0; mt < 4; ++mt)
                a[mt] = *(const longx2*)(xb + (wm * 64 + mt * 16 + l15) * 64 + quad * 16);
            if (kc8 < 4) {
                #pragma unroll
                for (int nt = 0; nt < 4; ++nt) b[nt] = bc[kc8][nt];
            } else {
                #pragma unroll
                for (int nt = 0; nt < 4; ++nt)
                    b[nt] = *(const longx2*)(XnHi + (wn * 64 + nt * 16 + l15) * 272 +
                                             (kc8 - 4) * 64 + quad * 16);
            }
            #pragma unroll
            for (int mt = 0; mt < 4; ++mt)
                #pragma unroll
                for (int nt = 0; nt < 4; ++nt)
                    accG[mt][nt] = __builtin_amdgcn_mfma_f32_16x16x32_fp8_fp8(
                        a[mt][0], b[nt][0], accG[mt][nt], 0, 0, 0);
            #pragma unroll
            for (int mt = 0; mt < 4; ++mt)
                #pragma unroll
                for (int nt = 0; nt < 4; ++nt)
                    accG[mt][nt] = __builtin_amdgcn_mfma_f32_16x16x32_fp8_fp8(
                        a[mt][1], b[nt][1], accG[mt][nt], 0, 0, 0);
            if (stage) {
                unsigned char* xd = Xi[(kc8 + 1) & 1];
                *(uint4*)(xd + t * 16)        = qA;
                *(uint4*)(xd + t * 16 + 4096) = qB;
            }
        }

        // ---- epilogue: d2 -> exp -> packed bf16 (accG dies here)
        uint2 pk[4][4];
        #pragma unroll
        for (int mt = 0; mt < 4; ++mt) {
            f32x4 si = *(const f32x4*)(sq + i0 + wm * 64 + mt * 16 + quad * 4);
            #pragma unroll
            for (int nt = 0; nt < 4; ++nt) {
                float sn = sqn_v[nt];
                union { __bf16 h[4]; uint2 u; } u;
                #pragma unroll
                for (int r = 0; r < 4; ++r) {
                    float d2 = si[r] + sn - 2.0f * accG[mt][nt][r];
                    u.h[r] = (__bf16)__expf(d2 * -9.765625e-4f);   // exp(-d2/1024)
                }
                pk[mt][nt] = u.u;
            }
        }

        const __bf16* wslab = WTs + (size_t)(i0 >> 5) * 2048;
        bf16x8 aw[2][4];
        #pragma unroll
        for (int kc2 = 0; kc2 < 2; ++kc2)
            for (int st = 0; st < 4; ++st)
                aw[kc2][st] = *(const bf16x8*)(wslab + kc2 * 2048 +
                                               (st * 16 + l15) * 32 + quad * 8);

        __syncthreads();   // A: prev it's E-phase KT reads done
        if (wm == 0) {     // half 0: i-local 0..63 (C layout col=l15(n), row=quad*4+r)
            #pragma unroll
            for (int mt = 0; mt < 4; ++mt)
                for (int nt = 0; nt < 4; ++nt)
                    *(uint2*)(KT + (wn * 64 + nt * 16 + l15) * 72 + mt * 16 + quad * 4)
                        = pk[mt][nt];
        }
        __syncthreads();   // B: KT half-0 visible
        #pragma unroll
        for (int kc2 = 0; kc2 < 2; ++kc2) {
            bf16x8 bk[2];
            for (int n2 = 0; n2 < 2; ++n2)
                bk[n2] = *(const bf16x8*)(KT + (w * 32 + n2 * 16 + l15) * 72 +
                                          kc2 * 32 + quad * 8);
            #pragma unroll
            for (int st = 0; st < 4; ++st)
                for (int n2 = 0; n2 < 2; ++n2)
                    accE[st][n2] = __builtin_amdgcn_mfma_f32_16x16x32_bf16(
                        aw[kc2][st], bk[n2], accE[st][n2], 0, 0, 0);
        }
        #pragma unroll
        for (int kc2 = 0; kc2 < 2; ++kc2)      // second half (kc2 2,3)
            for (int st = 0; st < 4; ++st)
                aw[kc2][st] = *(const bf16x8*)(wslab + (kc2 + 2) * 2048 +
                                               (st * 16 + l15) * 32 + quad * 8);
        __syncthreads();   // C: half-0 E reads done
        if (wm == 1) {     // half 1: i-local 64..127
            #pragma unroll
            for (int mt = 0; mt < 4; ++mt)
                for (int nt = 0; nt < 4; ++nt)
                    *(uint2*)(KT + (wn * 64 + nt * 16 + l15) * 72 + mt * 16 + quad * 4)
                        = pk[mt][nt];
        }
        __syncthreads();   // D: KT half-1 visible
        #pragma unroll
        for (int kc2 = 0; kc2 < 2; ++kc2) {
            bf16x8 bk[2];
            for (int n2 = 0; n2 < 2; ++n2)
                bk[n2] = *(const bf16x8*)(KT + (w * 32 + n2 * 16 + l15) * 72 +
                                          kc2 * 32 + quad * 8);
            #pragma unroll
            for (int st = 0; st < 4; ++st)
                for (int n2 = 0; n2 < 2; ++n2)
                    accE[st][n2] = __builtin_amdgcn_mfma_f32_16x16x32_bf16(
                        aw[kc2][st], bk[n2], accE[st][n2], 0, 0, 0);
        }
    }

    // ---- per-chunk E partial: plain stores
    float* ep = Ep + (size_t)blockIdx.y * (NS * N);
    #pragma unroll
    for (int st = 0; st < 4; ++st)
        for (int n2 = 0; n2 < 2; ++n2)
            for (int r = 0; r < 4; ++r) {
                int s = st * 16 + quad * 4 + r;
                int n = n0 + w * 32 + n2 * 16 + l15;
                ep[(size_t)s * N + n] = accE[st][n2][r];
            }
}

// ---------------------------------------------------------------------------
// loss: 256 blocks = 64 s x 4 n-chunks; sums the 8 E partials, reduces;
// last block finalizes the scalar.
__global__ __launch_bounds__(256) void loss_kernel(const float* __restrict__ Ep,
                                                   const __bf16* __restrict__ WTs,
                                                   const float* __restrict__ lam,
                                                   float* __restrict__ Sacc,
                                                   float* __restrict__ out) {
    int s = blockIdx.x >> 2;
    int nb = (blockIdx.x & 3) * 2048;
    int t = threadIdx.x;
    float a1 = 0.f, a2 = 0.f;
    for (int j = 0; j < 8; ++j) {
        int n = nb + t + j * 256;
        float e = 0.f;
        #pragma unroll
        for (int c = 0; c < 8; ++c)
            e += Ep[(size_t)c * (NS * N) + (size_t)s * N + n];
        a1 += e * e;
        a2 += e * (float)WTs[(size_t)(n >> 5) * 2048 + s * 32 + (n & 31)];
    }
    for (int off = 32; off > 0; off >>= 1) {
        a1 += __shfl_down(a1, off);
        a2 += __shfl_down(a2, off);
    }
    __shared__ float r1[4], r2[4];
    int wv = t >> 6, ln = t & 63;
    if (ln == 0) { r1[wv] = a1; r2[wv] = a2; }
    __syncthreads();
    if (t == 0) {
        atomicAdd(Sacc + 0, lam[s] * (r1[0] + r1[1] + r1[2] + r1[3]));
        atomicAdd(Sacc + 1, r2[0] + r2[1] + r2[2] + r2[3]);
        __threadfence();
        int prev = atomicAdd((int*)Sacc + 2, 1);
        if (prev == 255) {                       // last block finalizes
            __threadfence();
            volatile float* vs = (volatile float*)Sacc;
            float L = 0.5f * (vs[1] - vs[0]);    // loss1=-S1/2, loss2=S2/2
            out[0] = L + 0.05f * L * L;          // C_STAB/2 = 0.05
        }
    }
}

// ---------------------------------------------------------------------------
extern "C" void kernel_launch(void* const* d_in, const int* in_sizes, int n_in,
                              void* d_out, int out_size, void* d_ws, size_t ws_size,
                              hipStream_t stream) {
    const float* X   = (const float*)d_in[0];   // [8192][512]
    const float* W   = (const float*)d_in[1];   // [8192][64]
    const float* lam = (const float*)d_in[2];   // [64]
    float* out = (float*)d_out;
    char* ws = (char*)d_ws;
    unsigned char* Xs = (unsigned char*)(ws + XS_OFF);
    __bf16* WTs = (__bf16*)(ws + WT_OFF);
    float* sq   = (float*)(ws + SQ_OFF);
    float* Ep   = (float*)(ws + EP_OFF);
    float* Sacc = (float*)(ws + SC_OFF);

    prep<<<2048 + 128, 256, 0, stream>>>(X, W, Xs, sq, WTs, Sacc);
    kpca_main<<<dim3(64, 8), 256, 0, stream>>>(Xs, WTs, sq, Ep);
    loss_kernel<<<256, 256, 0, stream>>>(Ep, WTs, lam, Sacc, out);
}